// Round 1
// baseline (396.998 us; speedup 1.0000x reference)
//
#include <hip/hip_runtime.h>
#include <math.h>

// RotatedIoULoss: per-pair rotated-box IoU loss, mean-reduced to one f32 scalar.
// Inputs: d_in[0]=pred (n,5) f32, d_in[1]=target (n,5) f32, d_in[2]=weight (n,) f32.
// Output: d_out[0] = mean(-log(max(iou,1e-6)) * weight).

__device__ __forceinline__ float cross2f(float ax, float ay, float bx, float by) {
    return ax * by - ay * bx;
}

__global__ void __launch_bounds__(256)
riou_loss_kernel(const float* __restrict__ pred,
                 const float* __restrict__ target,
                 const float* __restrict__ weight,
                 float* __restrict__ out,
                 int n, float inv_n)
{
    int idx = blockIdx.x * blockDim.x + threadIdx.x;
    float loss = 0.0f;

    if (idx < n) {
        const float tx[4] = {0.5f, -0.5f, -0.5f, 0.5f};
        const float ty[4] = {0.5f, 0.5f, -0.5f, -0.5f};

        const float* P = pred   + (size_t)idx * 5;
        const float* Q = target + (size_t)idx * 5;
        float px = P[0], py = P[1], pw = P[2], ph = P[3], pa = P[4];
        float qx = Q[0], qy = Q[1], qw = Q[2], qh = Q[3], qa = Q[4];

        float ca = cosf(pa), sa = sinf(pa);
        float cb = cosf(qa), sb = sinf(qa);

        float c1x[4], c1y[4], c2x[4], c2y[4];
        #pragma unroll
        for (int i = 0; i < 4; i++) {
            float cx = tx[i] * pw, cy = ty[i] * ph;
            c1x[i] = cx * ca - cy * sa + px;
            c1y[i] = cx * sa + cy * ca + py;
            float dx = tx[i] * qw, dy = ty[i] * qh;
            c2x[i] = dx * cb - dy * sb + qx;
            c2y[i] = dx * sb + dy * cb + qy;
        }

        // Candidate vertices, collected in the reference's concatenation order:
        // c1 corners (mask m1), c2 corners (mask m2), 16 edge intersections.
        float vx[24], vy[24];
        int nv = 0;
        float sx = 0.f, sy = 0.f;

        // corners of box1 strictly inside box2 (projection onto edges AB, AD of c2)
        {
            float abx = c2x[1] - c2x[0], aby = c2y[1] - c2y[0];
            float adx = c2x[3] - c2x[0], ady = c2y[3] - c2y[0];
            float nab = abx * abx + aby * aby;
            float nad = adx * adx + ady * ady;
            #pragma unroll
            for (int i = 0; i < 4; i++) {
                float amx = c1x[i] - c2x[0], amy = c1y[i] - c2y[0];
                float pab = amx * abx + amy * aby;
                float pad = amx * adx + amy * ady;
                if (pab > 0.f && pab < nab && pad > 0.f && pad < nad) {
                    vx[nv] = c1x[i]; vy[nv] = c1y[i];
                    sx += c1x[i]; sy += c1y[i]; nv++;
                }
            }
        }
        // corners of box2 strictly inside box1
        {
            float abx = c1x[1] - c1x[0], aby = c1y[1] - c1y[0];
            float adx = c1x[3] - c1x[0], ady = c1y[3] - c1y[0];
            float nab = abx * abx + aby * aby;
            float nad = adx * adx + ady * ady;
            #pragma unroll
            for (int i = 0; i < 4; i++) {
                float amx = c2x[i] - c1x[0], amy = c2y[i] - c1y[0];
                float pab = amx * abx + amy * aby;
                float pad = amx * adx + amy * ady;
                if (pab > 0.f && pab < nab && pad > 0.f && pad < nad) {
                    vx[nv] = c2x[i]; vy[nv] = c2y[i];
                    sx += c2x[i]; sy += c2y[i]; nv++;
                }
            }
        }
        // edge-edge intersections (i over box1 edges outer, j over box2 edges inner,
        // matching the reference's reshape(n,16) order)
        #pragma unroll
        for (int i = 0; i < 4; i++) {
            float p1x = c1x[i], p1y = c1y[i];
            float d1x = c1x[(i + 1) & 3] - p1x, d1y = c1y[(i + 1) & 3] - p1y;
            #pragma unroll
            for (int j = 0; j < 4; j++) {
                float p2x = c2x[j], p2y = c2y[j];
                float d2x = c2x[(j + 1) & 3] - p2x, d2y = c2y[(j + 1) & 3] - p2y;
                float den = cross2f(d1x, d1y, d2x, d2y);
                float dpx = p2x - p1x, dpy = p2y - p1y;
                float safe = (den == 0.f) ? 1.f : den;
                float t = cross2f(dpx, dpy, d2x, d2y) / safe;
                float u = cross2f(dpx, dpy, d1x, d1y) / safe;
                if (den != 0.f && t > 0.f && t < 1.f && u > 0.f && u < 1.f) {
                    float ix = fmaf(t, d1x, p1x);
                    float iy = fmaf(t, d1y, p1y);
                    // match reference's p1 + t*d1 without fma contraction surprises:
                    ix = p1x + t * d1x;
                    iy = p1y + t * d1y;
                    vx[nv] = ix; vy[nv] = iy;
                    sx += ix; sy += iy; nv++;
                }
            }
        }

        float inter = 0.f;
        if (nv >= 3) {
            float cx = sx / (float)nv, cy = sy / (float)nv;
            float ang[24];
            for (int k = 0; k < nv; k++)
                ang[k] = atan2f(vy[k] - cy, vx[k] - cx);
            // stable insertion sort by angle (matches jnp.argsort stable ascending)
            for (int a = 1; a < nv; a++) {
                float A = ang[a], X = vx[a], Y = vy[a];
                int b = a - 1;
                while (b >= 0 && ang[b] > A) {
                    ang[b + 1] = ang[b]; vx[b + 1] = vx[b]; vy[b + 1] = vy[b];
                    b--;
                }
                ang[b + 1] = A; vx[b + 1] = X; vy[b + 1] = Y;
            }
            float area2 = 0.f;
            for (int k = 0; k < nv; k++) {
                int kn = (k + 1 == nv) ? 0 : k + 1;
                area2 += cross2f(vx[k], vy[k], vx[kn], vy[kn]);
            }
            inter = 0.5f * fabsf(area2);
        }

        float a1 = pw * ph;
        float a2 = qw * qh;
        float iou = inter / (a1 + a2 - inter);
        iou = fmaxf(iou, 1e-6f);
        loss = -logf(iou) * weight[idx];
    }

    // block reduction: wave shuffle (width 64) -> LDS -> one atomic per block
    #pragma unroll
    for (int off = 32; off > 0; off >>= 1)
        loss += __shfl_down(loss, off, 64);

    __shared__ float ssum[4];
    int wave = threadIdx.x >> 6;
    int lane = threadIdx.x & 63;
    if (lane == 0) ssum[wave] = loss;
    __syncthreads();
    if (threadIdx.x == 0) {
        float s = ssum[0] + ssum[1] + ssum[2] + ssum[3];
        atomicAdd(out, s * inv_n);
    }
}

extern "C" void kernel_launch(void* const* d_in, const int* in_sizes, int n_in,
                              void* d_out, int out_size, void* d_ws, size_t ws_size,
                              hipStream_t stream) {
    const float* pred   = (const float*)d_in[0];
    const float* target = (const float*)d_in[1];
    const float* weight = (const float*)d_in[2];
    float* out = (float*)d_out;

    int n = in_sizes[0] / 5;

    // d_out is poisoned to 0xAA before every timed launch -> zero it ourselves.
    hipMemsetAsync(out, 0, sizeof(float), stream);

    int block = 256;
    int grid = (n + block - 1) / block;
    riou_loss_kernel<<<grid, block, 0, stream>>>(pred, target, weight, out,
                                                 n, 1.0f / (float)n);
}

// Round 2
// 127.302 us; speedup vs baseline: 3.1186x; 3.1186x over previous
//
#include <hip/hip_runtime.h>
#include <math.h>

// RotatedIoULoss: per-pair rotated-box IoU loss, mean-reduced to one f32 scalar.
// Inputs: d_in[0]=pred (n,5) f32, d_in[1]=target (n,5) f32, d_in[2]=weight (n,) f32.
// Output: d_out[0] = mean(-log(max(iou,1e-6)) * weight).
//
// R1: branchless Green's-theorem intersection area (Liang-Barsky edge clipping),
// replacing the R0 compaction + atan2 + insertion-sort path that forced scratch
// arrays / movrel waterfalls and divergent loops. No private arrays with dynamic
// indices, no libcalls except sincos/log.

__global__ void __launch_bounds__(256)
riou_loss_kernel(const float* __restrict__ pred,
                 const float* __restrict__ target,
                 const float* __restrict__ weight,
                 float* __restrict__ out,
                 int n, float inv_n)
{
    int idx = blockIdx.x * blockDim.x + threadIdx.x;
    float loss = 0.0f;

    if (idx < n) {
        const float* P = pred   + (size_t)idx * 5;
        const float* Q = target + (size_t)idx * 5;
        float px = P[0], py = P[1], pw = P[2], ph = P[3], pa = P[4];
        float qx = Q[0], qy = Q[1], qw = Q[2], qh = Q[3], qa = Q[4];

        float ca = __cosf(pa), sa = __sinf(pa);
        float cb = __cosf(qa), sb = __sinf(qa);
        // work in box1-local frame (translate by (px,py)) to keep cross-product
        // magnitudes ~50 instead of ~512 -> no shoelace cancellation
        float ox = qx - px, oy = qy - py;

        const float tx[4] = {0.5f, -0.5f, -0.5f, 0.5f};
        const float ty[4] = {0.5f, 0.5f, -0.5f, -0.5f};

        // corners (CCW) of both boxes, static unroll, all indices compile-time
        float c1x[4], c1y[4], c2x[4], c2y[4];
        #pragma unroll
        for (int i = 0; i < 4; i++) {
            float cx = tx[i] * pw, cy = ty[i] * ph;
            c1x[i] = cx * ca - cy * sa;
            c1y[i] = cx * sa + cy * ca;
            float dx = tx[i] * qw, dy = ty[i] * qh;
            c2x[i] = dx * cb - dy * sb + ox;
            c2y[i] = dx * sb + dy * cb + oy;
        }
        float e1x[4], e1y[4], e2x[4], e2y[4];
        #pragma unroll
        for (int i = 0; i < 4; i++) {
            e1x[i] = c1x[(i + 1) & 3] - c1x[i];
            e1y[i] = c1y[(i + 1) & 3] - c1y[i];
            e2x[i] = c2x[(i + 1) & 3] - c2x[i];
            e2y[i] = c2y[(i + 1) & 3] - c2y[i];
        }

        // 2*Area(P ∩ Q) = sum of cross(start,end) over boundary pieces:
        //   edges of P clipped to Q  +  edges of Q clipped to P  (any order).
        float acc = 0.0f;

        #pragma unroll
        for (int s = 0; s < 2; s++) {
            const float* ax_ = s ? c2x : c1x;
            const float* ay_ = s ? c2y : c1y;
            const float* dx_ = s ? e2x : e1x;
            const float* dy_ = s ? e2y : e1y;
            const float* bx_ = s ? c1x : c2x;
            const float* by_ = s ? c1y : c2y;
            const float* fx_ = s ? e1x : e2x;
            const float* fy_ = s ? e1y : e2y;

            #pragma unroll
            for (int i = 0; i < 4; i++) {
                float ax = ax_[i], ay = ay_[i];
                float dx = dx_[i], dy = dy_[i];
                float t0 = 0.0f, t1 = 1.0f;
                bool dead = false;
                #pragma unroll
                for (int j = 0; j < 4; j++) {
                    // inside(q-halfplane j): cross(e_j, p - q_j) >= 0
                    // along segment: f + t*g >= 0
                    float g = fx_[j] * dy - fy_[j] * dx;
                    float f = fx_[j] * (ay - by_[j]) - fy_[j] * (ax - bx_[j]);
                    float t = -f * __builtin_amdgcn_rcpf(g);
                    t0 = fmaxf(t0, (g > 0.0f) ? t : 0.0f);
                    t1 = fminf(t1, (g < 0.0f) ? t : 1.0f);
                    dead = dead || ((g == 0.0f) && (f < 0.0f));
                }
                bool valid = (t1 > t0) && !dead;
                float sx = ax + t0 * dx, sy = ay + t0 * dy;
                float ex = ax + t1 * dx, ey = ay + t1 * dy;
                float c = sx * ey - sy * ex;
                acc += valid ? c : 0.0f;
            }
        }

        float inter = fmaxf(0.5f * acc, 0.0f);
        float a1 = pw * ph;
        float a2 = qw * qh;
        float iou = inter / (a1 + a2 - inter);
        iou = fmaxf(iou, 1e-6f);
        loss = -__logf(iou) * weight[idx];
    }

    // block reduction: wave shuffle (width 64) -> LDS -> one atomic per block
    #pragma unroll
    for (int off = 32; off > 0; off >>= 1)
        loss += __shfl_down(loss, off, 64);

    __shared__ float ssum[4];
    int wave = threadIdx.x >> 6;
    int lane = threadIdx.x & 63;
    if (lane == 0) ssum[wave] = loss;
    __syncthreads();
    if (threadIdx.x == 0) {
        float s = ssum[0] + ssum[1] + ssum[2] + ssum[3];
        atomicAdd(out, s * inv_n);
    }
}

extern "C" void kernel_launch(void* const* d_in, const int* in_sizes, int n_in,
                              void* d_out, int out_size, void* d_ws, size_t ws_size,
                              hipStream_t stream) {
    const float* pred   = (const float*)d_in[0];
    const float* target = (const float*)d_in[1];
    const float* weight = (const float*)d_in[2];
    float* out = (float*)d_out;

    int n = in_sizes[0] / 5;

    // d_out is poisoned to 0xAA before every timed launch -> zero it ourselves.
    hipMemsetAsync(out, 0, sizeof(float), stream);

    int block = 256;
    int grid = (n + block - 1) / block;
    riou_loss_kernel<<<grid, block, 0, stream>>>(pred, target, weight, out,
                                                 n, 1.0f / (float)n);
}

// Round 3
// 98.509 us; speedup vs baseline: 4.0301x; 1.2923x over previous
//
#include <hip/hip_runtime.h>
#include <math.h>

// RotatedIoULoss: per-pair rotated-box IoU loss, mean-reduced to one f32 scalar.
// Inputs: d_in[0]=pred (n,5) f32, d_in[1]=target (n,5) f32, d_in[2]=weight (n,) f32.
// Output: d_out[0] = mean(-log(max(iou,1e-6)) * weight).
//
// R1: branchless Green's-theorem intersection (Liang-Barsky clipping).
// R2: 4 boxes/thread -> five aligned float4 loads per input (was 20 strided
//     dwords) + 4 independent geometry pipelines per lane for ILP to cover
//     load latency and the min/max clip dependency chains.

__device__ __forceinline__ float riou_one(float pw, float ph, float pa,
                                          float ox, float oy,
                                          float qw, float qh, float qa,
                                          float w)
{
    float ca = __cosf(pa), sa = __sinf(pa);
    float cb = __cosf(qa), sb = __sinf(qa);

    const float tx[4] = {0.5f, -0.5f, -0.5f, 0.5f};
    const float ty[4] = {0.5f, 0.5f, -0.5f, -0.5f};

    float c1x[4], c1y[4], c2x[4], c2y[4];
    #pragma unroll
    for (int i = 0; i < 4; i++) {
        float cx = tx[i] * pw, cy = ty[i] * ph;
        c1x[i] = cx * ca - cy * sa;
        c1y[i] = cx * sa + cy * ca;
        float dx = tx[i] * qw, dy = ty[i] * qh;
        c2x[i] = dx * cb - dy * sb + ox;
        c2y[i] = dx * sb + dy * cb + oy;
    }
    float e1x[4], e1y[4], e2x[4], e2y[4];
    #pragma unroll
    for (int i = 0; i < 4; i++) {
        e1x[i] = c1x[(i + 1) & 3] - c1x[i];
        e1y[i] = c1y[(i + 1) & 3] - c1y[i];
        e2x[i] = c2x[(i + 1) & 3] - c2x[i];
        e2y[i] = c2y[(i + 1) & 3] - c2y[i];
    }

    // 2*Area(P ∩ Q) = sum over boundary pieces of cross(start,end):
    // edges of P clipped to Q + edges of Q clipped to P (order-independent).
    float acc = 0.0f;
    #pragma unroll
    for (int s = 0; s < 2; s++) {
        const float* ax_ = s ? c2x : c1x;
        const float* ay_ = s ? c2y : c1y;
        const float* dx_ = s ? e2x : e1x;
        const float* dy_ = s ? e2y : e1y;
        const float* bx_ = s ? c1x : c2x;
        const float* by_ = s ? c1y : c2y;
        const float* fx_ = s ? e1x : e2x;
        const float* fy_ = s ? e1y : e2y;

        #pragma unroll
        for (int i = 0; i < 4; i++) {
            float ax = ax_[i], ay = ay_[i];
            float dx = dx_[i], dy = dy_[i];
            float t0 = 0.0f, t1 = 1.0f;
            bool dead = false;
            #pragma unroll
            for (int j = 0; j < 4; j++) {
                // inside(halfplane j): f + t*g >= 0
                float g = fx_[j] * dy - fy_[j] * dx;
                float f = fx_[j] * (ay - by_[j]) - fy_[j] * (ax - bx_[j]);
                float t = -f * __builtin_amdgcn_rcpf(g);
                t0 = fmaxf(t0, (g > 0.0f) ? t : 0.0f);
                t1 = fminf(t1, (g < 0.0f) ? t : 1.0f);
                dead = dead || ((g == 0.0f) && (f < 0.0f));
            }
            bool valid = (t1 > t0) && !dead;
            float sx = ax + t0 * dx, sy = ay + t0 * dy;
            float ex = ax + t1 * dx, ey = ay + t1 * dy;
            float c = sx * ey - sy * ex;
            acc += valid ? c : 0.0f;
        }
    }

    float inter = fmaxf(0.5f * acc, 0.0f);
    float a1 = pw * ph;
    float a2 = qw * qh;
    float iou = inter * __builtin_amdgcn_rcpf(a1 + a2 - inter);
    iou = fmaxf(iou, 1e-6f);
    return -__logf(iou) * w;
}

__global__ void __launch_bounds__(256)
riou_loss_kernel(const float* __restrict__ pred,
                 const float* __restrict__ target,
                 const float* __restrict__ weight,
                 float* __restrict__ out,
                 int n, float inv_n)
{
    int t = blockIdx.x * blockDim.x + threadIdx.x;
    int base = t * 4;
    float loss = 0.0f;

    if (base < n) {
        float pp[20], qq[20], ww[4];
        if (base + 4 <= n) {
            // 80 B per thread, 16B-aligned: five float4 loads per input
            const float4* P4 = (const float4*)(pred   + (size_t)base * 5);
            const float4* Q4 = (const float4*)(target + (size_t)base * 5);
            #pragma unroll
            for (int i = 0; i < 5; i++) {
                float4 p = P4[i];
                pp[4 * i + 0] = p.x; pp[4 * i + 1] = p.y;
                pp[4 * i + 2] = p.z; pp[4 * i + 3] = p.w;
                float4 q = Q4[i];
                qq[4 * i + 0] = q.x; qq[4 * i + 1] = q.y;
                qq[4 * i + 2] = q.z; qq[4 * i + 3] = q.w;
            }
            float4 w4 = ((const float4*)weight)[t];
            ww[0] = w4.x; ww[1] = w4.y; ww[2] = w4.z; ww[3] = w4.w;
        } else {
            #pragma unroll
            for (int k = 0; k < 4; k++) {
                int b = base + k; b = (b < n) ? b : (n - 1);
                #pragma unroll
                for (int j = 0; j < 5; j++) {
                    pp[5 * k + j] = pred[(size_t)b * 5 + j];
                    qq[5 * k + j] = target[(size_t)b * 5 + j];
                }
                ww[k] = (base + k < n) ? weight[b] : 0.0f;
            }
            // tail path stores box-major (5*k+j); rearrange flag below
        }

        bool vec = (base + 4 <= n);
        #pragma unroll
        for (int k = 0; k < 4; k++) {
            // vec path: pp is flat row-major over 20 floats -> box k at 5*k..5*k+4
            // (same layout either way, since 4*i+c enumerates 0..19 in order)
            float px = pp[5 * k + 0], py = pp[5 * k + 1];
            float pw = pp[5 * k + 2], ph = pp[5 * k + 3], pa = pp[5 * k + 4];
            float qx = qq[5 * k + 0], qy = qq[5 * k + 1];
            float qw = qq[5 * k + 2], qh = qq[5 * k + 3], qa = qq[5 * k + 4];
            float w  = (vec || base + k < n) ? ww[k] : 0.0f;
            // translate to box1-local frame to keep magnitudes small
            loss += riou_one(pw, ph, pa, qx - px, qy - py, qw, qh, qa, w);
        }
    }

    // block reduction: wave shuffle (width 64) -> LDS -> one atomic per block
    #pragma unroll
    for (int off = 32; off > 0; off >>= 1)
        loss += __shfl_down(loss, off, 64);

    __shared__ float ssum[4];
    int wave = threadIdx.x >> 6;
    int lane = threadIdx.x & 63;
    if (lane == 0) ssum[wave] = loss;
    __syncthreads();
    if (threadIdx.x == 0) {
        float s = ssum[0] + ssum[1] + ssum[2] + ssum[3];
        atomicAdd(out, s * inv_n);
    }
}

extern "C" void kernel_launch(void* const* d_in, const int* in_sizes, int n_in,
                              void* d_out, int out_size, void* d_ws, size_t ws_size,
                              hipStream_t stream) {
    const float* pred   = (const float*)d_in[0];
    const float* target = (const float*)d_in[1];
    const float* weight = (const float*)d_in[2];
    float* out = (float*)d_out;

    int n = in_sizes[0] / 5;

    // d_out is poisoned to 0xAA before every timed launch -> zero it ourselves.
    hipMemsetAsync(out, 0, sizeof(float), stream);

    int block = 256;
    int threads_needed = (n + 3) / 4;
    int grid = (threads_needed + block - 1) / block;
    riou_loss_kernel<<<grid, block, 0, stream>>>(pred, target, weight, out,
                                                 n, 1.0f / (float)n);
}

// Round 4
// 93.718 us; speedup vs baseline: 4.2361x; 1.0511x over previous
//
#include <hip/hip_runtime.h>
#include <math.h>

// RotatedIoULoss: per-pair rotated-box IoU loss, mean-reduced to one f32 scalar.
// Inputs: d_in[0]=pred (n,5) f32, d_in[1]=target (n,5) f32, d_in[2]=weight (n,) f32.
// Output: d_out[0] = mean(-log(max(iou,1e-6)) * weight).
//
// R1: branchless Green's-theorem intersection (generic halfplane Liang-Barsky).
// R2: 4 boxes/thread, float4 loads, 4 independent pipelines for ILP.
// R3: exploit rectangle structure — clip each box's edges against the OTHER
//     box's frame as an AABB slab clip (2 rcp + min/max per edge instead of
//     4 generic halfplane tests), only 2 distinct edge vectors per quad
//     (4 rcp/set instead of 16/pair). The two sets are computed in different
//     local frames; Green pieces are combined with the closed-form translation
//     correction 2A = S_A + S_B + cross(cQ, R_PQ * D_B), D_B = sum(e - s).
//     ~330 VALU-equiv/box vs ~800 in R2.

__device__ __forceinline__ float rcpf(float x) { return __builtin_amdgcn_rcpf(x); }

// Clip one edge (start (u0,v0), direction (dx,dy), reciprocal dir (rx,ry))
// against the AABB [-hw,hw]x[-hh,hh]; accumulate Green cross term and (if
// TRACK) the net displacement of the valid piece.
template <bool TRACK>
__device__ __forceinline__ void clip_edge(float u0, float v0, float dx, float dy,
                                          float rx, float ry, float hw, float hh,
                                          float& S, float& Dx, float& Dy)
{
    float ta = (-hw - u0) * rx;
    float tb = ( hw - u0) * rx;
    float tc = (-hh - v0) * ry;
    float td = ( hh - v0) * ry;
    float tumin = fminf(ta, tb), tumax = fmaxf(ta, tb);
    float tvmin = fminf(tc, td), tvmax = fmaxf(tc, td);
    float t0 = fmaxf(fmaxf(tumin, tvmin), 0.0f);   // v_max3
    float t1 = fminf(fminf(tumax, tvmax), 1.0f);   // v_min3
    bool valid = t1 > t0;
    float sx = fmaf(t0, dx, u0), sy = fmaf(t0, dy, v0);
    float ex = fmaf(t1, dx, u0), ey = fmaf(t1, dy, v0);
    float c = sx * ey - sy * ex;
    S += valid ? c : 0.0f;
    if (TRACK) {
        Dx += valid ? (ex - sx) : 0.0f;
        Dy += valid ? (ey - sy) : 0.0f;
    }
}

// Quad with CCW corners (+U+V, -U+V, -U-V, +U-V) + c, clipped to AABB(hw,hh).
// Edge vectors are (-2U, -2V, +2U, +2V) -> only 4 distinct rcps.
template <bool TRACK>
__device__ __forceinline__ float clip_quad(float Ux, float Uy, float Vx, float Vy,
                                           float cx, float cy, float hw, float hh,
                                           float& Dx, float& Dy)
{
    float d0x = -2.0f * Ux, d0y = -2.0f * Uy;   // edge 0 and (negated) edge 2
    float d1x = -2.0f * Vx, d1y = -2.0f * Vy;   // edge 1 and (negated) edge 3
    float r0x = rcpf(d0x), r0y = rcpf(d0y);
    float r1x = rcpf(d1x), r1y = rcpf(d1y);

    float sxv = Ux + Vx, syv = Uy + Vy;   // c0 offset
    float dxv = Ux - Vx, dyv = Uy - Vy;   // c3 offset

    float S = 0.0f;
    // c0 = ( sx, sy)+c, d0
    clip_edge<TRACK>( sxv + cx,  syv + cy,  d0x,  d0y,  r0x,  r0y, hw, hh, S, Dx, Dy);
    // c1 = (-dx,-dy)+c, d1
    clip_edge<TRACK>(-dxv + cx, -dyv + cy,  d1x,  d1y,  r1x,  r1y, hw, hh, S, Dx, Dy);
    // c2 = (-sx,-sy)+c, -d0
    clip_edge<TRACK>(-sxv + cx, -syv + cy, -d0x, -d0y, -r0x, -r0y, hw, hh, S, Dx, Dy);
    // c3 = ( dx, dy)+c, -d1
    clip_edge<TRACK>( dxv + cx,  dyv + cy, -d1x, -d1y, -r1x, -r1y, hw, hh, S, Dx, Dy);
    return S;
}

__device__ __forceinline__ float riou_one(float px, float py, float pw, float ph, float pa,
                                          float qx, float qy, float qw, float qh, float qa,
                                          float w)
{
    float hw1 = 0.5f * pw, hh1 = 0.5f * ph;
    float hw2 = 0.5f * qw, hh2 = 0.5f * qh;

    float ca = __cosf(pa), sa = __sinf(pa);
    float delta = pa - qa;
    float cr = __cosf(delta), sr = __sinf(delta);

    float ox = qx - px, oy = qy - py;          // q - p in world frame
    // Q center in P-frame: R(-pa) * o
    float cPx =  ca * ox + sa * oy;
    float cPy = -sa * ox + ca * oy;
    // P center in Q-frame: cQ = -R_PQ * cP, R_PQ = [cr -sr; sr cr]
    float cQx = -(cr * cPx - sr * cPy);
    float cQy = -(sr * cPx + cr * cPy);

    // Set A: P's quad in Q-frame, clip box (hw2,hh2).
    //   U = R_PQ*(hw1,0) = (cr*hw1, sr*hw1); V = R_PQ*(0,hh1) = (-sr*hh1, cr*hh1)
    float dum0 = 0.0f, dum1 = 0.0f;
    float SA = clip_quad<false>(cr * hw1, sr * hw1, -sr * hh1, cr * hh1,
                                cQx, cQy, hw2, hh2, dum0, dum1);

    // Set B: Q's quad in P-frame, clip box (hw1,hh1). Track D for the
    // frame-translation correction.
    //   U = R_QP*(hw2,0) = (cr*hw2, -sr*hw2); V = R_QP*(0,hh2) = (sr*hh2, cr*hh2)
    float Dx = 0.0f, Dy = 0.0f;
    float SB = clip_quad<true>(cr * hw2, -sr * hw2, sr * hh2, cr * hh2,
                               cPx, cPy, hw1, hh1, Dx, Dy);

    // corr = cross(cQ, R_PQ * D)
    float RDx = cr * Dx - sr * Dy;
    float RDy = sr * Dx + cr * Dy;
    float corr = cQx * RDy - cQy * RDx;

    float inter = fmaxf(0.5f * (SA + SB + corr), 0.0f);
    float a1 = pw * ph;
    float a2 = qw * qh;
    float iou = inter * rcpf(a1 + a2 - inter);
    iou = fmaxf(iou, 1e-6f);
    return -__logf(iou) * w;
}

__global__ void __launch_bounds__(256)
riou_loss_kernel(const float* __restrict__ pred,
                 const float* __restrict__ target,
                 const float* __restrict__ weight,
                 float* __restrict__ out,
                 int n, float inv_n)
{
    int t = blockIdx.x * blockDim.x + threadIdx.x;
    int base = t * 4;
    float loss = 0.0f;

    if (base < n) {
        float pp[20], qq[20], ww[4];
        if (base + 4 <= n) {
            // 80 B per thread, 16B-aligned: five float4 loads per input
            const float4* P4 = (const float4*)(pred   + (size_t)base * 5);
            const float4* Q4 = (const float4*)(target + (size_t)base * 5);
            #pragma unroll
            for (int i = 0; i < 5; i++) {
                float4 p = P4[i];
                pp[4 * i + 0] = p.x; pp[4 * i + 1] = p.y;
                pp[4 * i + 2] = p.z; pp[4 * i + 3] = p.w;
                float4 q = Q4[i];
                qq[4 * i + 0] = q.x; qq[4 * i + 1] = q.y;
                qq[4 * i + 2] = q.z; qq[4 * i + 3] = q.w;
            }
            float4 w4 = ((const float4*)weight)[t];
            ww[0] = w4.x; ww[1] = w4.y; ww[2] = w4.z; ww[3] = w4.w;
        } else {
            #pragma unroll
            for (int k = 0; k < 4; k++) {
                int b = base + k; b = (b < n) ? b : (n - 1);
                #pragma unroll
                for (int j = 0; j < 5; j++) {
                    pp[5 * k + j] = pred[(size_t)b * 5 + j];
                    qq[5 * k + j] = target[(size_t)b * 5 + j];
                }
                ww[k] = (base + k < n) ? weight[b] : 0.0f;
            }
        }

        #pragma unroll
        for (int k = 0; k < 4; k++) {
            loss += riou_one(pp[5 * k + 0], pp[5 * k + 1], pp[5 * k + 2],
                             pp[5 * k + 3], pp[5 * k + 4],
                             qq[5 * k + 0], qq[5 * k + 1], qq[5 * k + 2],
                             qq[5 * k + 3], qq[5 * k + 4],
                             ww[k]);
        }
    }

    // block reduction: wave shuffle (width 64) -> LDS -> one atomic per block
    #pragma unroll
    for (int off = 32; off > 0; off >>= 1)
        loss += __shfl_down(loss, off, 64);

    __shared__ float ssum[4];
    int wave = threadIdx.x >> 6;
    int lane = threadIdx.x & 63;
    if (lane == 0) ssum[wave] = loss;
    __syncthreads();
    if (threadIdx.x == 0) {
        float s = ssum[0] + ssum[1] + ssum[2] + ssum[3];
        atomicAdd(out, s * inv_n);
    }
}

extern "C" void kernel_launch(void* const* d_in, const int* in_sizes, int n_in,
                              void* d_out, int out_size, void* d_ws, size_t ws_size,
                              hipStream_t stream) {
    const float* pred   = (const float*)d_in[0];
    const float* target = (const float*)d_in[1];
    const float* weight = (const float*)d_in[2];
    float* out = (float*)d_out;

    int n = in_sizes[0] / 5;

    // d_out is poisoned to 0xAA before every timed launch -> zero it ourselves.
    hipMemsetAsync(out, 0, sizeof(float), stream);

    int block = 256;
    int threads_needed = (n + 3) / 4;
    int grid = (threads_needed + block - 1) / block;
    riou_loss_kernel<<<grid, block, 0, stream>>>(pred, target, weight, out,
                                                 n, 1.0f / (float)n);
}